// Round 8
// baseline (183.221 us; speedup 1.0000x reference)
//
#include <hip/hip_runtime.h>

#define B 128
#define N 65536
#define D 512
#define K 5
#define M 256              // D * RATIO
#define GPB 128            // gallery rows per block (kernel1)
#define NBLK1 (N / GPB)    // 512 blocks
#define CHG 16             // fallback: g rows per chunk
#define NCHK (GPB / CHG)   // fallback: 8

typedef __attribute__((ext_vector_type(8))) short short8;
typedef __attribute__((ext_vector_type(4))) float f32x4;
typedef __attribute__((address_space(1))) const unsigned char as1cu8;
typedef __attribute__((address_space(3))) unsigned char as3u8;

// pack two fp32 -> one u32 of 2 bf16 (truncation) via v_perm_b32.
__device__ __forceinline__ unsigned int pack_bf2(float lo, float hi) {
    return __builtin_amdgcn_perm(__float_as_uint(hi), __float_as_uint(lo), 0x07060302u);
}

__device__ __forceinline__ void top5_insert(float v, int gi, float tv[K], int ti[K]) {
    // descending by value, ties broken by lower index (matches lax.top_k)
    if (v > tv[K - 1] || (v == tv[K - 1] && gi < ti[K - 1])) {
        tv[K - 1] = v; ti[K - 1] = gi;
        #pragma unroll
        for (int k = K - 1; k > 0; --k) {
            bool sw = (tv[k] > tv[k - 1]) || (tv[k] == tv[k - 1] && ti[k] < ti[k - 1]);
            if (sw) {
                float fv = tv[k]; tv[k] = tv[k - 1]; tv[k - 1] = fv;
                int fi = ti[k]; ti[k] = ti[k - 1]; ti[k - 1] = fi;
            }
        }
    }
}

// k0t: t_f (128x512 fp32) -> bf16 once.
__global__ __launch_bounds__(256) void k0_cvt_t(const float* __restrict__ t_f,
                                                unsigned int* __restrict__ t_bf) {
    int i = blockIdx.x * 256 + threadIdx.x;   // float4 index, 16384 total
    float4 v = reinterpret_cast<const float4*>(t_f)[i];
    uint2 p;
    p.x = pack_bf2(v.x, v.y);
    p.y = pack_bf2(v.z, v.w);
    reinterpret_cast<uint2*>(t_bf)[i] = p;
}

// k0g: gallery fp32 -> bf16 (64 MB) + fp32 row inv-norms. One wave per row,
// unit-stride 2KB per wave: pure streaming at HBM rate.
__global__ __launch_bounds__(256) void k0_cvt_g(const float* __restrict__ gal,
                                                uint4* __restrict__ gal_bf4,
                                                float* __restrict__ invnorm) {
    const int row = blockIdx.x * 4 + (threadIdx.x >> 6);
    const int lane = threadIdx.x & 63;
    const float* rp = gal + (size_t)row * D + lane * 8;
    float4 a = *reinterpret_cast<const float4*>(rp);
    float4 b = *reinterpret_cast<const float4*>(rp + 4);
    float s = 0.f;
    s = fmaf(a.x, a.x, s); s = fmaf(a.y, a.y, s);
    s = fmaf(a.z, a.z, s); s = fmaf(a.w, a.w, s);
    s = fmaf(b.x, b.x, s); s = fmaf(b.y, b.y, s);
    s = fmaf(b.z, b.z, s); s = fmaf(b.w, b.w, s);
    #pragma unroll
    for (int m = 1; m < 64; m <<= 1) s += __shfl_xor(s, m);
    uint4 q;
    q.x = pack_bf2(a.x, a.y); q.y = pack_bf2(a.z, a.w);
    q.z = pack_bf2(b.x, b.y); q.w = pack_bf2(b.z, b.w);
    gal_bf4[(size_t)row * 64 + lane] = q;
    if (lane == 0) invnorm[row] = rsqrtf(fmaxf(s, 1e-24f));
}

// k1 (main): whole 128x512 bf16 gallery tile staged to 128KB LDS via
// global_load_lds DMA (linear LDS dest, inverse-XOR-swizzled global source,
// XOR-swizzled ds_read: rule #21). ONE barrier per block; then each wave does
// 128 ds_read_b128 + 128 MFMA straight through. Norms precomputed (k0g).
__global__ __launch_bounds__(512) void k1_dma(const unsigned short* __restrict__ t_bf,
                                              const unsigned short* __restrict__ gal_bf,
                                              const float* __restrict__ invnorm,
                                              float2* __restrict__ partial) {
    __shared__ __align__(16) unsigned short gT[GPB * D];   // 131072 B

    const int tid = threadIdx.x;
    const int blk = blockIdx.x;
    const int lane = tid & 63;
    const int w = tid >> 6;
    const int l15 = lane & 15;
    const int l4 = lane >> 4;

    // ---- issue gallery DMA: wave w stages rows [16w, 16w+16), 1KB per inst ----
    const size_t grow0 = (size_t)blk * GPB;
    const char* gbytes = reinterpret_cast<const char*>(gal_bf);
    #pragma unroll
    for (int j = 0; j < 16; ++j) {
        const int r = 16 * w + j;
        // LDS[r][cb] must hold gal(r, cb ^ ((r&7)<<4)); DMA writes lane l at cb=l*16
        const char* src = gbytes + (grow0 + r) * (size_t)(D * 2) + ((lane * 16) ^ ((j & 7) << 4));
        char* dst = reinterpret_cast<char*>(gT) + r * 1024;      // wave-uniform
        __builtin_amdgcn_global_load_lds((as1cu8*)src, (as3u8*)dst, 16, 0, 0);
    }

    // ---- A fragments: wave's 16 b-rows (row = l15), bf16, pinned (64 VGPR) ----
    short8 afr[16];
    {
        const unsigned short* tp = t_bf + (size_t)(w * 16 + l15) * D + l4 * 8;
        #pragma unroll
        for (int ks = 0; ks < 16; ++ks) {
            uint4 q = *reinterpret_cast<const uint4*>(tp + ks * 32);
            asm volatile("" : "+v"(q.x), "+v"(q.y), "+v"(q.z), "+v"(q.w));
            afr[ks] = *reinterpret_cast<short8*>(&q);
        }
    }

    // ---- invnorm prefetch: scale for g-col gg*16 + l15 ----
    float invn[8];
    #pragma unroll
    for (int gg = 0; gg < 8; ++gg) invn[gg] = invnorm[blk * GPB + gg * 16 + l15];

    // packed top-5 lists: lst[r] for b-row w*16 + l4*4 + r, over g ≡ l15 (mod 16)
    float lst[4][K];
    #pragma unroll
    for (int r = 0; r < 4; ++r)
        #pragma unroll
        for (int k = 0; k < K; ++k) lst[r][k] = -1e30f;

    __syncthreads();   // single barrier: drains DMA (compiler emits vmcnt(0))

    auto ins = [&](const f32x4& a, float sc, int gcol) {
        unsigned meta = (unsigned)gcol;
        #pragma unroll
        for (int r = 0; r < 4; ++r) {
            float s = a[r] * sc;
            float sp = __uint_as_float((__float_as_uint(s) & 0xFFFFFF00u) | meta);
            if (sp > lst[r][K - 1]) {
                lst[r][K - 1] = sp;
                #pragma unroll
                for (int k = K - 1; k > 0; --k)
                    if (lst[r][k] > lst[r][k - 1]) {
                        float t2 = lst[r][k]; lst[r][k] = lst[r][k - 1]; lst[r][k - 1] = t2;
                    }
            }
        }
    };

    const char* LB = reinterpret_cast<const char*>(gT);
    const int xr = (l15 & 7) << 4;
    #pragma unroll
    for (int gg = 0; gg < 8; gg += 2) {
        f32x4 acc0 = (f32x4)0.f, acc1 = (f32x4)0.f;
        const int r0 = gg * 16 + l15, r1 = (gg + 1) * 16 + l15;
        #pragma unroll
        for (int ks = 0; ks < 16; ++ks) {
            const int cb = (ks * 64 + l4 * 16) ^ xr;
            short8 b0 = *reinterpret_cast<const short8*>(LB + r0 * 1024 + cb);
            short8 b1 = *reinterpret_cast<const short8*>(LB + r1 * 1024 + cb);
            acc0 = __builtin_amdgcn_mfma_f32_16x16x32_bf16(afr[ks], b0, acc0, 0, 0, 0);
            acc1 = __builtin_amdgcn_mfma_f32_16x16x32_bf16(afr[ks], b1, acc1, 0, 0, 0);
        }
        ins(acc0, invn[gg], gg * 16 + l15);
        ins(acc1, invn[gg + 1], (gg + 1) * 16 + l15);
    }

    // merge the 16 g-residues within each l4 group (lists stay packed)
    #pragma unroll
    for (int mk = 1; mk <= 8; mk <<= 1) {
        #pragma unroll
        for (int r = 0; r < 4; ++r) {
            float inc[K];
            #pragma unroll
            for (int k = 0; k < K; ++k) inc[k] = __shfl_xor(lst[r][k], mk);
            #pragma unroll
            for (int k = 0; k < K; ++k) {
                if (inc[k] > lst[r][K - 1]) {
                    lst[r][K - 1] = inc[k];
                    #pragma unroll
                    for (int q = K - 1; q > 0; --q)
                        if (lst[r][q] > lst[r][q - 1]) {
                            float t2 = lst[r][q]; lst[r][q] = lst[r][q - 1]; lst[r][q - 1] = t2;
                        }
                }
            }
        }
    }

    #pragma unroll
    for (int rr = 0; rr < 4; ++rr) {
        if (l15 == rr) {
            int b = w * 16 + l4 * 4 + rr;
            #pragma unroll
            for (int k = 0; k < K; ++k) {
                unsigned sp = __float_as_uint(lst[rr][k]);
                int g = blk * GPB + (int)(sp & 0xFFu);
                partial[((size_t)b * NBLK1 + blk) * K + k] = make_float2(lst[rr][k], __int_as_float(g));
            }
        }
    }
}

// k1 fallback (R7 path, used when ws_size can't hold the bf16 gallery)
__global__ __launch_bounds__(512) void k1_fb(const unsigned short* __restrict__ t_bf,
                                             const float* __restrict__ gal,
                                             float2* __restrict__ partial) {
    __shared__ __align__(16) unsigned short gLds[2][CHG * D];
    __shared__ float normP[2][CHG];

    const int tid = threadIdx.x;
    const int blk = (blockIdx.x & 7) * (NBLK1 / 8) + (blockIdx.x >> 3);
    const int lane = tid & 63;
    const int w = tid >> 6;
    const int l15 = lane & 15;
    const int l4 = lane >> 4;
    const int bh = lane >> 3;
    const int colb = (lane & 7) * 8;
    const int xr = bh << 4;
    const int rb = l15 * 64 + l4 * 16;

    short8 afr[16];
    {
        const unsigned short* tp = t_bf + (size_t)(w * 16 + l15) * D + l4 * 8;
        #pragma unroll
        for (int ks = 0; ks < 16; ++ks) {
            uint4 q = *reinterpret_cast<const uint4*>(tp + ks * 32);
            asm volatile("" : "+v"(q.x), "+v"(q.y), "+v"(q.z), "+v"(q.w));
            afr[ks] = *reinterpret_cast<short8*>(&q);
        }
    }

    float lst[4][K];
    #pragma unroll
    for (int r = 0; r < 4; ++r)
        #pragma unroll
        for (int k = 0; k < K; ++k) lst[r][k] = -1e30f;

    const float* gbase = gal + ((size_t)blk * GPB + 2 * w) * D + lane * 4;

#define LOADSET(R0, R1, R2, R3, CIDX) do { \
        const float* gp_ = gbase + (size_t)(CIDX) * (CHG * D); \
        R0 = *reinterpret_cast<const float4*>(gp_); \
        R1 = *reinterpret_cast<const float4*>(gp_ + 256); \
        R2 = *reinterpret_cast<const float4*>(gp_ + 512); \
        R3 = *reinterpret_cast<const float4*>(gp_ + 768); \
    } while (0)

#define STAGE(R0, R1, R2, R3, BUFI) do { \
        char* LB_ = reinterpret_cast<char*>(&gLds[BUFI][0]); \
        uint2 q_; \
        q_.x = pack_bf2(R0.x, R0.y); q_.y = pack_bf2(R0.z, R0.w); \
        *reinterpret_cast<uint2*>(LB_ + (bh)      * 1024 + (((2 * w) * 64 + colb) ^ xr)) = q_; \
        q_.x = pack_bf2(R1.x, R1.y); q_.y = pack_bf2(R1.z, R1.w); \
        *reinterpret_cast<uint2*>(LB_ + (8 + bh)  * 1024 + (((2 * w) * 64 + colb) ^ xr)) = q_; \
        q_.x = pack_bf2(R2.x, R2.y); q_.y = pack_bf2(R2.z, R2.w); \
        *reinterpret_cast<uint2*>(LB_ + (bh)      * 1024 + (((2 * w + 1) * 64 + colb) ^ xr)) = q_; \
        q_.x = pack_bf2(R3.x, R3.y); q_.y = pack_bf2(R3.z, R3.w); \
        *reinterpret_cast<uint2*>(LB_ + (8 + bh)  * 1024 + (((2 * w + 1) * 64 + colb) ^ xr)) = q_; \
        float nrA_ = 0.f, nrB_ = 0.f; \
        nrA_ = fmaf(R0.x, R0.x, nrA_); nrA_ = fmaf(R0.y, R0.y, nrA_); \
        nrA_ = fmaf(R0.z, R0.z, nrA_); nrA_ = fmaf(R0.w, R0.w, nrA_); \
        nrA_ = fmaf(R1.x, R1.x, nrA_); nrA_ = fmaf(R1.y, R1.y, nrA_); \
        nrA_ = fmaf(R1.z, R1.z, nrA_); nrA_ = fmaf(R1.w, R1.w, nrA_); \
        nrB_ = fmaf(R2.x, R2.x, nrB_); nrB_ = fmaf(R2.y, R2.y, nrB_); \
        nrB_ = fmaf(R2.z, R2.z, nrB_); nrB_ = fmaf(R2.w, R2.w, nrB_); \
        nrB_ = fmaf(R3.x, R3.x, nrB_); nrB_ = fmaf(R3.y, R3.y, nrB_); \
        nrB_ = fmaf(R3.z, R3.z, nrB_); nrB_ = fmaf(R3.w, R3.w, nrB_); \
        _Pragma("unroll") \
        for (int s_ = 1; s_ < 64; s_ <<= 1) { \
            nrA_ += __shfl_xor(nrA_, s_); \
            nrB_ += __shfl_xor(nrB_, s_); \
        } \
        if (lane == 0) { normP[BUFI][2 * w] = nrA_; normP[BUFI][2 * w + 1] = nrB_; } \
    } while (0)

#define COMPUTE(BUFI, CIDX) do { \
        f32x4 acc0_ = (f32x4)0.f, acc1_ = (f32x4)0.f; \
        const char* LB_ = reinterpret_cast<const char*>(&gLds[BUFI][0]); \
        _Pragma("unroll") \
        for (int ks_ = 0; ks_ < 16; ks_ += 2) { \
            short8 b0_ = *reinterpret_cast<const short8*>(LB_ + ks_ * 1024 + (rb ^ ((ks_ & 7) << 4))); \
            short8 b1_ = *reinterpret_cast<const short8*>(LB_ + (ks_ + 1) * 1024 + (rb ^ (((ks_ + 1) & 7) << 4))); \
            acc0_ = __builtin_amdgcn_mfma_f32_16x16x32_bf16(afr[ks_], b0_, acc0_, 0, 0, 0); \
            acc1_ = __builtin_amdgcn_mfma_f32_16x16x32_bf16(afr[ks_ + 1], b1_, acc1_, 0, 0, 0); \
        } \
        float sc_ = rsqrtf(normP[BUFI][l15]); \
        unsigned meta_ = (unsigned)((CIDX) * CHG + l15); \
        _Pragma("unroll") \
        for (int r_ = 0; r_ < 4; ++r_) { \
            float s_ = (acc0_[r_] + acc1_[r_]) * sc_; \
            float sp_ = __uint_as_float((__float_as_uint(s_) & 0xFFFFFF00u) | meta_); \
            if (sp_ > lst[r_][K - 1]) { \
                lst[r_][K - 1] = sp_; \
                _Pragma("unroll") \
                for (int k_ = K - 1; k_ > 0; --k_) \
                    if (lst[r_][k_] > lst[r_][k_ - 1]) { \
                        float t_ = lst[r_][k_]; lst[r_][k_] = lst[r_][k_ - 1]; lst[r_][k_ - 1] = t_; \
                    } \
            } \
        } \
    } while (0)

    float4 A0, A1, A2, A3, B0, B1, B2, B3;
    LOADSET(A0, A1, A2, A3, 0);
    LOADSET(B0, B1, B2, B3, 1);
    STAGE(A0, A1, A2, A3, 0);
    __syncthreads();

    #pragma unroll
    for (int cc = 0; cc < NCHK; cc += 2) {
        if (cc + 2 < NCHK) LOADSET(A0, A1, A2, A3, cc + 2);
        if (cc + 1 < NCHK) STAGE(B0, B1, B2, B3, 1);
        COMPUTE(0, cc);
        __syncthreads();
        if (cc + 3 < NCHK) LOADSET(B0, B1, B2, B3, cc + 3);
        if (cc + 2 < NCHK) STAGE(A0, A1, A2, A3, 0);
        COMPUTE(1, cc + 1);
        __syncthreads();
    }

    #pragma unroll
    for (int mk = 1; mk <= 8; mk <<= 1) {
        #pragma unroll
        for (int r = 0; r < 4; ++r) {
            float inc[K];
            #pragma unroll
            for (int k = 0; k < K; ++k) inc[k] = __shfl_xor(lst[r][k], mk);
            #pragma unroll
            for (int k = 0; k < K; ++k) {
                if (inc[k] > lst[r][K - 1]) {
                    lst[r][K - 1] = inc[k];
                    #pragma unroll
                    for (int q = K - 1; q > 0; --q)
                        if (lst[r][q] > lst[r][q - 1]) {
                            float t2 = lst[r][q]; lst[r][q] = lst[r][q - 1]; lst[r][q - 1] = t2;
                        }
                }
            }
        }
    }

    #pragma unroll
    for (int rr = 0; rr < 4; ++rr) {
        if (l15 == rr) {
            int b = w * 16 + l4 * 4 + rr;
            #pragma unroll
            for (int k = 0; k < K; ++k) {
                unsigned sp = __float_as_uint(lst[rr][k]);
                int g = blk * GPB + (int)(sp & 0xFFu);
                partial[((size_t)b * NBLK1 + blk) * K + k] = make_float2(lst[rr][k], __int_as_float(g));
            }
        }
    }
#undef LOADSET
#undef STAGE
#undef COMPUTE
}

// k2: merge 512 partial top-5 lists per batch row -> top_idx. Block 0 inits
// the AND bitmap + completion counter (runs before k34 in stream order).
__global__ __launch_bounds__(512) void k2_merge(const float2* __restrict__ partial,
                                               int* __restrict__ top_idx,
                                               unsigned long long* __restrict__ mask64,
                                               unsigned int* __restrict__ counter) {
    __shared__ float2 cand[NBLK1 * K];  // 20480 B
    const int b = blockIdx.x;
    const int p = threadIdx.x;
    if (b == 0) {
        if (p < (D / 64)) mask64[p] = ~0ull;
        if (p == 8) *counter = 0u;
    }

    float mv[K]; int mi[K];
    #pragma unroll
    for (int k = 0; k < K; ++k) {
        float2 c = partial[((size_t)b * NBLK1 + p) * K + k];
        mv[k] = c.x; mi[k] = __float_as_int(c.y);
        cand[p * K + k] = c;
    }
    __syncthreads();
    for (int s = NBLK1 / 2; s >= 1; s >>= 1) {
        if (p < s) {
            #pragma unroll
            for (int k = 0; k < K; ++k) {
                float2 c = cand[(p + s) * K + k];
                top5_insert(c.x, __float_as_int(c.y), mv, mi);
            }
            #pragma unroll
            for (int k = 0; k < K; ++k)
                cand[p * K + k] = make_float2(mv[k], __int_as_float(mi[k]));
        }
        __syncthreads();
    }
    if (p == 0) {
        #pragma unroll
        for (int k = 0; k < K; ++k) top_idx[b * K + k] = mi[k];
    }
}

// k34: one block per (b,k) row (640 blocks, 5x the parallelism of the fused
// version): bottom-m membership of |gal[row,c]*s_f[b,c]| (per-row norms are
// positive constants -> same ordering as the reference's normalized products),
// AND into bitmap; LAST block emits the output mask.
__global__ __launch_bounds__(512) void k34_member(const float* __restrict__ s_f,
                                                  const float* __restrict__ gal,
                                                  const int* __restrict__ top_idx,
                                                  unsigned long long* __restrict__ mask64,
                                                  unsigned int* __restrict__ counter,
                                                  float* __restrict__ out) {
    __shared__ __align__(16) float pS[D];
    __shared__ unsigned long long maskLds[D / 64];
    __shared__ int isLast;
    const int p = threadIdx.x;
    const int bk = blockIdx.x;
    const int b = bk / K;
    const int row = top_idx[bk];
    float pv = fabsf(gal[(size_t)row * D + p] * s_f[(size_t)b * D + p]);
    pS[p] = pv;
    __syncthreads();
    int cnt = 0;
    const float4* p4 = reinterpret_cast<const float4*>(pS);
    #pragma unroll 4
    for (int j = 0; j < D / 4; ++j) {
        float4 o = p4[j];
        cnt += (o.x < pv || (o.x == pv && (4 * j + 0) < p)) ? 1 : 0;
        cnt += (o.y < pv || (o.y == pv && (4 * j + 1) < p)) ? 1 : 0;
        cnt += (o.z < pv || (o.z == pv && (4 * j + 2) < p)) ? 1 : 0;
        cnt += (o.w < pv || (o.w == pv && (4 * j + 3) < p)) ? 1 : 0;
    }
    unsigned long long bm = __ballot(cnt < M);
    if ((p & 63) == 0) atomicAnd(&mask64[p >> 6], bm);
    __syncthreads();
    if (p == 0) {
        __threadfence();
        unsigned done = atomicAdd(counter, 1u);
        isLast = (done == (unsigned)(B * K - 1)) ? 1 : 0;
    }
    __syncthreads();
    if (isLast) {
        if (p < (D / 64)) {
            __threadfence();
            maskLds[p] = atomicAnd(&mask64[p], ~0ull);   // coherent read
        }
        __syncthreads();
        out[p] = ((maskLds[p >> 6] >> (p & 63)) & 1ull) ? 0.0f : 1.0f;
    }
}

extern "C" void kernel_launch(void* const* d_in, const int* in_sizes, int n_in,
                              void* d_out, int out_size, void* d_ws, size_t ws_size,
                              hipStream_t stream) {
    (void)in_sizes; (void)n_in; (void)out_size;
    const float* s_f = (const float*)d_in[0];
    const float* t_f = (const float*)d_in[1];
    const float* gal = (const float*)d_in[2];
    float* out = (float*)d_out;

    char* ws = (char*)d_ws;
    const size_t off_tbf     = 0;                       // 131072
    const size_t off_partial = 131072;                  // 2621440
    const size_t off_topidx  = off_partial + 2621440;   // 2560
    const size_t off_mask    = off_topidx + 2560;       // 64
    const size_t off_cnt     = off_mask + 64;           // 64
    const size_t off_invn    = off_cnt + 64;            // 262144
    const size_t off_galbf   = off_invn + 262144;       // 67108864
    const size_t NEED        = off_galbf + 67108864;

    unsigned int* t_bf = (unsigned int*)(ws + off_tbf);
    float2* partial = (float2*)(ws + off_partial);
    int* top_idx = (int*)(ws + off_topidx);
    unsigned long long* mask64 = (unsigned long long*)(ws + off_mask);
    unsigned int* counter = (unsigned int*)(ws + off_cnt);
    float* invnorm = (float*)(ws + off_invn);
    unsigned short* gal_bf = (unsigned short*)(ws + off_galbf);

    hipLaunchKernelGGL(k0_cvt_t, dim3(B * D / 4 / 256), dim3(256), 0, stream, t_f, t_bf);
    if (ws_size >= NEED) {
        hipLaunchKernelGGL(k0_cvt_g, dim3(N / 4), dim3(256), 0, stream,
                           gal, (uint4*)gal_bf, invnorm);
        hipLaunchKernelGGL(k1_dma, dim3(NBLK1), dim3(512), 0, stream,
                           (const unsigned short*)t_bf, gal_bf, invnorm, partial);
    } else {
        hipLaunchKernelGGL(k1_fb, dim3(NBLK1), dim3(512), 0, stream,
                           (const unsigned short*)t_bf, gal, partial);
    }
    hipLaunchKernelGGL(k2_merge, dim3(B), dim3(512), 0, stream,
                       partial, top_idx, mask64, counter);
    hipLaunchKernelGGL(k34_member, dim3(B * K), dim3(512), 0, stream,
                       s_f, gal, top_idx, mask64, counter, out);
}

// Round 9
// 170.282 us; speedup vs baseline: 1.0760x; 1.0760x over previous
//
#include <hip/hip_runtime.h>

#define B 128
#define N 65536
#define D 512
#define K 5
#define M 256              // D * RATIO
#define GPB 128            // gallery rows per block (kernel1)
#define NBLK1 (N / GPB)    // 512 blocks
#define CHG 16             // fallback: g rows per chunk
#define NCHK (GPB / CHG)   // fallback: 8

typedef __attribute__((ext_vector_type(8))) short short8;
typedef __attribute__((ext_vector_type(4))) float f32x4;
typedef __attribute__((address_space(1))) const unsigned char as1cu8;
typedef __attribute__((address_space(3))) unsigned char as3u8;

// pack two fp32 -> one u32 of 2 bf16 (truncation) via v_perm_b32.
__device__ __forceinline__ unsigned int pack_bf2(float lo, float hi) {
    return __builtin_amdgcn_perm(__float_as_uint(hi), __float_as_uint(lo), 0x07060302u);
}

__device__ __forceinline__ void top5_insert(float v, int gi, float tv[K], int ti[K]) {
    // descending by value, ties broken by lower index (matches lax.top_k)
    if (v > tv[K - 1] || (v == tv[K - 1] && gi < ti[K - 1])) {
        tv[K - 1] = v; ti[K - 1] = gi;
        #pragma unroll
        for (int k = K - 1; k > 0; --k) {
            bool sw = (tv[k] > tv[k - 1]) || (tv[k] == tv[k - 1] && ti[k] < ti[k - 1]);
            if (sw) {
                float fv = tv[k]; tv[k] = tv[k - 1]; tv[k - 1] = fv;
                int fi = ti[k]; ti[k] = ti[k - 1]; ti[k - 1] = fi;
            }
        }
    }
}

// k0t: t_f (128x512 fp32) -> bf16 once.
__global__ __launch_bounds__(256) void k0_cvt_t(const float* __restrict__ t_f,
                                                unsigned int* __restrict__ t_bf) {
    int i = blockIdx.x * 256 + threadIdx.x;   // float4 index, 16384 total
    float4 v = reinterpret_cast<const float4*>(t_f)[i];
    uint2 p;
    p.x = pack_bf2(v.x, v.y);
    p.y = pack_bf2(v.z, v.w);
    reinterpret_cast<uint2*>(t_bf)[i] = p;
}

// k0g: gallery fp32 -> bf16 (64 MB) + fp32 row inv-norms. One wave per row.
__global__ __launch_bounds__(256) void k0_cvt_g(const float* __restrict__ gal,
                                                uint4* __restrict__ gal_bf4,
                                                float* __restrict__ invnorm) {
    const int row = blockIdx.x * 4 + (threadIdx.x >> 6);
    const int lane = threadIdx.x & 63;
    const float* rp = gal + (size_t)row * D + lane * 8;
    float4 a = *reinterpret_cast<const float4*>(rp);
    float4 b = *reinterpret_cast<const float4*>(rp + 4);
    float s = 0.f;
    s = fmaf(a.x, a.x, s); s = fmaf(a.y, a.y, s);
    s = fmaf(a.z, a.z, s); s = fmaf(a.w, a.w, s);
    s = fmaf(b.x, b.x, s); s = fmaf(b.y, b.y, s);
    s = fmaf(b.z, b.z, s); s = fmaf(b.w, b.w, s);
    #pragma unroll
    for (int m = 1; m < 64; m <<= 1) s += __shfl_xor(s, m);
    uint4 q;
    q.x = pack_bf2(a.x, a.y); q.y = pack_bf2(a.z, a.w);
    q.z = pack_bf2(b.x, b.y); q.w = pack_bf2(b.z, b.w);
    gal_bf4[(size_t)row * 64 + lane] = q;
    if (lane == 0) invnorm[row] = rsqrtf(fmaxf(s, 1e-24f));
}

// k1 (main): whole 128x512 bf16 gallery tile staged to 128KB LDS via
// global_load_lds DMA (linear LDS dest, inverse-XOR-swizzled global source,
// XOR-swizzled ds_read: rule #21). ONE barrier per block; then each wave does
// 128 ds_read_b128 + 128 MFMA straight through. Norms precomputed (k0g).
__global__ __launch_bounds__(512) void k1_dma(const unsigned short* __restrict__ t_bf,
                                              const unsigned short* __restrict__ gal_bf,
                                              const float* __restrict__ invnorm,
                                              float2* __restrict__ partial) {
    __shared__ __align__(16) unsigned short gT[GPB * D];   // 131072 B

    const int tid = threadIdx.x;
    const int blk = blockIdx.x;
    const int lane = tid & 63;
    const int w = tid >> 6;
    const int l15 = lane & 15;
    const int l4 = lane >> 4;

    // ---- issue gallery DMA: wave w stages rows [16w, 16w+16), 1KB per inst ----
    const size_t grow0 = (size_t)blk * GPB;
    const char* gbytes = reinterpret_cast<const char*>(gal_bf);
    #pragma unroll
    for (int j = 0; j < 16; ++j) {
        const int r = 16 * w + j;
        const char* src = gbytes + (grow0 + r) * (size_t)(D * 2) + ((lane * 16) ^ ((j & 7) << 4));
        char* dst = reinterpret_cast<char*>(gT) + r * 1024;      // wave-uniform
        __builtin_amdgcn_global_load_lds((as1cu8*)src, (as3u8*)dst, 16, 0, 0);
    }

    // ---- A fragments: wave's 16 b-rows (row = l15), bf16, pinned (64 VGPR) ----
    short8 afr[16];
    {
        const unsigned short* tp = t_bf + (size_t)(w * 16 + l15) * D + l4 * 8;
        #pragma unroll
        for (int ks = 0; ks < 16; ++ks) {
            uint4 q = *reinterpret_cast<const uint4*>(tp + ks * 32);
            asm volatile("" : "+v"(q.x), "+v"(q.y), "+v"(q.z), "+v"(q.w));
            afr[ks] = *reinterpret_cast<short8*>(&q);
        }
    }

    // ---- invnorm prefetch: scale for g-col gg*16 + l15 ----
    float invn[8];
    #pragma unroll
    for (int gg = 0; gg < 8; ++gg) invn[gg] = invnorm[blk * GPB + gg * 16 + l15];

    // packed top-5 lists: lst[r] for b-row w*16 + l4*4 + r, over g ≡ l15 (mod 16)
    float lst[4][K];
    #pragma unroll
    for (int r = 0; r < 4; ++r)
        #pragma unroll
        for (int k = 0; k < K; ++k) lst[r][k] = -1e30f;

    __syncthreads();   // single barrier: drains DMA (compiler emits vmcnt(0))

    auto ins = [&](const f32x4& a, float sc, int gcol) {
        unsigned meta = (unsigned)gcol;
        #pragma unroll
        for (int r = 0; r < 4; ++r) {
            float s = a[r] * sc;
            float sp = __uint_as_float((__float_as_uint(s) & 0xFFFFFF00u) | meta);
            if (sp > lst[r][K - 1]) {
                lst[r][K - 1] = sp;
                #pragma unroll
                for (int k = K - 1; k > 0; --k)
                    if (lst[r][k] > lst[r][k - 1]) {
                        float t2 = lst[r][k]; lst[r][k] = lst[r][k - 1]; lst[r][k - 1] = t2;
                    }
            }
        }
    };

    const char* LB = reinterpret_cast<const char*>(gT);
    const int xr = (l15 & 7) << 4;
    #pragma unroll
    for (int gg = 0; gg < 8; gg += 2) {
        f32x4 acc0 = (f32x4)0.f, acc1 = (f32x4)0.f;
        const int r0 = gg * 16 + l15, r1 = (gg + 1) * 16 + l15;
        #pragma unroll
        for (int ks = 0; ks < 16; ++ks) {
            const int cb = (ks * 64 + l4 * 16) ^ xr;
            short8 b0 = *reinterpret_cast<const short8*>(LB + r0 * 1024 + cb);
            short8 b1 = *reinterpret_cast<const short8*>(LB + r1 * 1024 + cb);
            acc0 = __builtin_amdgcn_mfma_f32_16x16x32_bf16(afr[ks], b0, acc0, 0, 0, 0);
            acc1 = __builtin_amdgcn_mfma_f32_16x16x32_bf16(afr[ks], b1, acc1, 0, 0, 0);
        }
        ins(acc0, invn[gg], gg * 16 + l15);
        ins(acc1, invn[gg + 1], (gg + 1) * 16 + l15);
    }

    // merge the 16 g-residues within each l4 group (lists stay packed)
    #pragma unroll
    for (int mk = 1; mk <= 8; mk <<= 1) {
        #pragma unroll
        for (int r = 0; r < 4; ++r) {
            float inc[K];
            #pragma unroll
            for (int k = 0; k < K; ++k) inc[k] = __shfl_xor(lst[r][k], mk);
            #pragma unroll
            for (int k = 0; k < K; ++k) {
                if (inc[k] > lst[r][K - 1]) {
                    lst[r][K - 1] = inc[k];
                    #pragma unroll
                    for (int q = K - 1; q > 0; --q)
                        if (lst[r][q] > lst[r][q - 1]) {
                            float t2 = lst[r][q]; lst[r][q] = lst[r][q - 1]; lst[r][q - 1] = t2;
                        }
                }
            }
        }
    }

    #pragma unroll
    for (int rr = 0; rr < 4; ++rr) {
        if (l15 == rr) {
            int b = w * 16 + l4 * 4 + rr;
            #pragma unroll
            for (int k = 0; k < K; ++k) {
                unsigned sp = __float_as_uint(lst[rr][k]);
                int g = blk * GPB + (int)(sp & 0xFFu);
                partial[((size_t)b * NBLK1 + blk) * K + k] = make_float2(lst[rr][k], __int_as_float(g));
            }
        }
    }
}

// k1 fallback (R7 path, used when ws_size can't hold the bf16 gallery)
__global__ __launch_bounds__(512) void k1_fb(const unsigned short* __restrict__ t_bf,
                                             const float* __restrict__ gal,
                                             float2* __restrict__ partial) {
    __shared__ __align__(16) unsigned short gLds[2][CHG * D];
    __shared__ float normP[2][CHG];

    const int tid = threadIdx.x;
    const int blk = (blockIdx.x & 7) * (NBLK1 / 8) + (blockIdx.x >> 3);
    const int lane = tid & 63;
    const int w = tid >> 6;
    const int l15 = lane & 15;
    const int l4 = lane >> 4;
    const int bh = lane >> 3;
    const int colb = (lane & 7) * 8;
    const int xr = bh << 4;
    const int rb = l15 * 64 + l4 * 16;

    short8 afr[16];
    {
        const unsigned short* tp = t_bf + (size_t)(w * 16 + l15) * D + l4 * 8;
        #pragma unroll
        for (int ks = 0; ks < 16; ++ks) {
            uint4 q = *reinterpret_cast<const uint4*>(tp + ks * 32);
            asm volatile("" : "+v"(q.x), "+v"(q.y), "+v"(q.z), "+v"(q.w));
            afr[ks] = *reinterpret_cast<short8*>(&q);
        }
    }

    float lst[4][K];
    #pragma unroll
    for (int r = 0; r < 4; ++r)
        #pragma unroll
        for (int k = 0; k < K; ++k) lst[r][k] = -1e30f;

    const float* gbase = gal + ((size_t)blk * GPB + 2 * w) * D + lane * 4;

#define LOADSET(R0, R1, R2, R3, CIDX) do { \
        const float* gp_ = gbase + (size_t)(CIDX) * (CHG * D); \
        R0 = *reinterpret_cast<const float4*>(gp_); \
        R1 = *reinterpret_cast<const float4*>(gp_ + 256); \
        R2 = *reinterpret_cast<const float4*>(gp_ + 512); \
        R3 = *reinterpret_cast<const float4*>(gp_ + 768); \
    } while (0)

#define STAGE(R0, R1, R2, R3, BUFI) do { \
        char* LB_ = reinterpret_cast<char*>(&gLds[BUFI][0]); \
        uint2 q_; \
        q_.x = pack_bf2(R0.x, R0.y); q_.y = pack_bf2(R0.z, R0.w); \
        *reinterpret_cast<uint2*>(LB_ + (bh)      * 1024 + (((2 * w) * 64 + colb) ^ xr)) = q_; \
        q_.x = pack_bf2(R1.x, R1.y); q_.y = pack_bf2(R1.z, R1.w); \
        *reinterpret_cast<uint2*>(LB_ + (8 + bh)  * 1024 + (((2 * w) * 64 + colb) ^ xr)) = q_; \
        q_.x = pack_bf2(R2.x, R2.y); q_.y = pack_bf2(R2.z, R2.w); \
        *reinterpret_cast<uint2*>(LB_ + (bh)      * 1024 + (((2 * w + 1) * 64 + colb) ^ xr)) = q_; \
        q_.x = pack_bf2(R3.x, R3.y); q_.y = pack_bf2(R3.z, R3.w); \
        *reinterpret_cast<uint2*>(LB_ + (8 + bh)  * 1024 + (((2 * w + 1) * 64 + colb) ^ xr)) = q_; \
        float nrA_ = 0.f, nrB_ = 0.f; \
        nrA_ = fmaf(R0.x, R0.x, nrA_); nrA_ = fmaf(R0.y, R0.y, nrA_); \
        nrA_ = fmaf(R0.z, R0.z, nrA_); nrA_ = fmaf(R0.w, R0.w, nrA_); \
        nrA_ = fmaf(R1.x, R1.x, nrA_); nrA_ = fmaf(R1.y, R1.y, nrA_); \
        nrA_ = fmaf(R1.z, R1.z, nrA_); nrA_ = fmaf(R1.w, R1.w, nrA_); \
        nrB_ = fmaf(R2.x, R2.x, nrB_); nrB_ = fmaf(R2.y, R2.y, nrB_); \
        nrB_ = fmaf(R2.z, R2.z, nrB_); nrB_ = fmaf(R2.w, R2.w, nrB_); \
        nrB_ = fmaf(R3.x, R3.x, nrB_); nrB_ = fmaf(R3.y, R3.y, nrB_); \
        nrB_ = fmaf(R3.z, R3.z, nrB_); nrB_ = fmaf(R3.w, R3.w, nrB_); \
        _Pragma("unroll") \
        for (int s_ = 1; s_ < 64; s_ <<= 1) { \
            nrA_ += __shfl_xor(nrA_, s_); \
            nrB_ += __shfl_xor(nrB_, s_); \
        } \
        if (lane == 0) { normP[BUFI][2 * w] = nrA_; normP[BUFI][2 * w + 1] = nrB_; } \
    } while (0)

#define COMPUTE(BUFI, CIDX) do { \
        f32x4 acc0_ = (f32x4)0.f, acc1_ = (f32x4)0.f; \
        const char* LB_ = reinterpret_cast<const char*>(&gLds[BUFI][0]); \
        _Pragma("unroll") \
        for (int ks_ = 0; ks_ < 16; ks_ += 2) { \
            short8 b0_ = *reinterpret_cast<const short8*>(LB_ + ks_ * 1024 + (rb ^ ((ks_ & 7) << 4))); \
            short8 b1_ = *reinterpret_cast<const short8*>(LB_ + (ks_ + 1) * 1024 + (rb ^ (((ks_ + 1) & 7) << 4))); \
            acc0_ = __builtin_amdgcn_mfma_f32_16x16x32_bf16(afr[ks_], b0_, acc0_, 0, 0, 0); \
            acc1_ = __builtin_amdgcn_mfma_f32_16x16x32_bf16(afr[ks_ + 1], b1_, acc1_, 0, 0, 0); \
        } \
        float sc_ = rsqrtf(normP[BUFI][l15]); \
        unsigned meta_ = (unsigned)((CIDX) * CHG + l15); \
        _Pragma("unroll") \
        for (int r_ = 0; r_ < 4; ++r_) { \
            float s_ = (acc0_[r_] + acc1_[r_]) * sc_; \
            float sp_ = __uint_as_float((__float_as_uint(s_) & 0xFFFFFF00u) | meta_); \
            if (sp_ > lst[r_][K - 1]) { \
                lst[r_][K - 1] = sp_; \
                _Pragma("unroll") \
                for (int k_ = K - 1; k_ > 0; --k_) \
                    if (lst[r_][k_] > lst[r_][k_ - 1]) { \
                        float t_ = lst[r_][k_]; lst[r_][k_] = lst[r_][k_ - 1]; lst[r_][k_ - 1] = t_; \
                    } \
            } \
        } \
    } while (0)

    float4 A0, A1, A2, A3, B0, B1, B2, B3;
    LOADSET(A0, A1, A2, A3, 0);
    LOADSET(B0, B1, B2, B3, 1);
    STAGE(A0, A1, A2, A3, 0);
    __syncthreads();

    #pragma unroll
    for (int cc = 0; cc < NCHK; cc += 2) {
        if (cc + 2 < NCHK) LOADSET(A0, A1, A2, A3, cc + 2);
        if (cc + 1 < NCHK) STAGE(B0, B1, B2, B3, 1);
        COMPUTE(0, cc);
        __syncthreads();
        if (cc + 3 < NCHK) LOADSET(B0, B1, B2, B3, cc + 3);
        if (cc + 2 < NCHK) STAGE(A0, A1, A2, A3, 0);
        COMPUTE(1, cc + 1);
        __syncthreads();
    }

    #pragma unroll
    for (int mk = 1; mk <= 8; mk <<= 1) {
        #pragma unroll
        for (int r = 0; r < 4; ++r) {
            float inc[K];
            #pragma unroll
            for (int k = 0; k < K; ++k) inc[k] = __shfl_xor(lst[r][k], mk);
            #pragma unroll
            for (int k = 0; k < K; ++k) {
                if (inc[k] > lst[r][K - 1]) {
                    lst[r][K - 1] = inc[k];
                    #pragma unroll
                    for (int q = K - 1; q > 0; --q)
                        if (lst[r][q] > lst[r][q - 1]) {
                            float t2 = lst[r][q]; lst[r][q] = lst[r][q - 1]; lst[r][q - 1] = t2;
                        }
                }
            }
        }
    }

    #pragma unroll
    for (int rr = 0; rr < 4; ++rr) {
        if (l15 == rr) {
            int b = w * 16 + l4 * 4 + rr;
            #pragma unroll
            for (int k = 0; k < K; ++k) {
                unsigned sp = __float_as_uint(lst[rr][k]);
                int g = blk * GPB + (int)(sp & 0xFFu);
                partial[((size_t)b * NBLK1 + blk) * K + k] = make_float2(lst[rr][k], __int_as_float(g));
            }
        }
    }
#undef LOADSET
#undef STAGE
#undef COMPUTE
}

// k2: merge 512 partial top-5 lists per batch row -> top_idx. Shuffle-first:
// 6 shfl_xor levels within each wave, then one LDS merge of the 8 wave lists.
// No device-scope atomics, no fences (R8 lesson: those cost ~70 us).
__global__ __launch_bounds__(512) void k2_merge(const float2* __restrict__ partial,
                                                int* __restrict__ top_idx) {
    __shared__ float2 wlist[8][K];
    const int b = blockIdx.x;
    const int p = threadIdx.x;
    const int lane = p & 63;
    const int w = p >> 6;

    float mv[K]; int mi[K];
    #pragma unroll
    for (int k = 0; k < K; ++k) {
        float2 c = partial[((size_t)b * NBLK1 + p) * K + k];
        mv[k] = c.x; mi[k] = __float_as_int(c.y);
    }
    #pragma unroll
    for (int mk = 1; mk <= 32; mk <<= 1) {
        float ov[K]; int oi[K];
        #pragma unroll
        for (int k = 0; k < K; ++k) { ov[k] = __shfl_xor(mv[k], mk); oi[k] = __shfl_xor(mi[k], mk); }
        #pragma unroll
        for (int k = 0; k < K; ++k) top5_insert(ov[k], oi[k], mv, mi);
    }
    if (lane == 0) {
        #pragma unroll
        for (int k = 0; k < K; ++k) wlist[w][k] = make_float2(mv[k], __int_as_float(mi[k]));
    }
    __syncthreads();
    if (w == 0) {
        #pragma unroll
        for (int k = 0; k < K; ++k) { mv[k] = -1e30f; mi[k] = 0x7fffffff; }
        if (lane < 8) {
            #pragma unroll
            for (int k = 0; k < K; ++k) {
                float2 c = wlist[lane][k];
                mv[k] = c.x; mi[k] = __float_as_int(c.y);
            }
        }
        #pragma unroll
        for (int mk = 1; mk <= 4; mk <<= 1) {
            float ov[K]; int oi[K];
            #pragma unroll
            for (int k = 0; k < K; ++k) { ov[k] = __shfl_xor(mv[k], mk); oi[k] = __shfl_xor(mi[k], mk); }
            #pragma unroll
            for (int k = 0; k < K; ++k) top5_insert(ov[k], oi[k], mv, mi);
        }
        if (lane == 0) {
            #pragma unroll
            for (int k = 0; k < K; ++k) top_idx[b * K + k] = mi[k];
        }
    }
}

// k3: one block per (b,k) row: bottom-m membership of |gal[row,c]*s_f[b,c]|
// (per-row norms are positive constants -> ordering matches the reference's
// normalized products). Result written with PLAIN stores (kernel-boundary
// coherence replaces atomics/fences).
__global__ __launch_bounds__(512) void k3_member(const float* __restrict__ s_f,
                                                 const float* __restrict__ gal,
                                                 const int* __restrict__ top_idx,
                                                 unsigned long long* __restrict__ bkmask) {
    __shared__ __align__(16) float pS[D];
    const int p = threadIdx.x;
    const int bk = blockIdx.x;
    const int b = bk / K;
    const int row = top_idx[bk];
    float pv = fabsf(gal[(size_t)row * D + p] * s_f[(size_t)b * D + p]);
    pS[p] = pv;
    __syncthreads();
    int cnt = 0;
    const float4* p4 = reinterpret_cast<const float4*>(pS);
    #pragma unroll 4
    for (int j = 0; j < D / 4; ++j) {
        float4 o = p4[j];
        cnt += (o.x < pv || (o.x == pv && (4 * j + 0) < p)) ? 1 : 0;
        cnt += (o.y < pv || (o.y == pv && (4 * j + 1) < p)) ? 1 : 0;
        cnt += (o.z < pv || (o.z == pv && (4 * j + 2) < p)) ? 1 : 0;
        cnt += (o.w < pv || (o.w == pv && (4 * j + 3) < p)) ? 1 : 0;
    }
    unsigned long long bm = __ballot(cnt < M);
    if ((p & 63) == 0) bkmask[(size_t)bk * 8 + (p >> 6)] = bm;
}

// k4: AND-reduce the 640 per-(b,k) masks, emit the output mask. 40 KB, L2-hot.
__global__ __launch_bounds__(512) void k4_final(const unsigned long long* __restrict__ bkmask,
                                                float* __restrict__ out) {
    const int c = threadIdx.x;
    const int word = c >> 6, bit = c & 63;
    unsigned long long acc = ~0ull;
    for (int bk = 0; bk < B * K; bk += 4) {
        acc &= bkmask[(size_t)bk * 8 + word];
        acc &= bkmask[(size_t)(bk + 1) * 8 + word];
        acc &= bkmask[(size_t)(bk + 2) * 8 + word];
        acc &= bkmask[(size_t)(bk + 3) * 8 + word];
    }
    out[c] = ((acc >> bit) & 1ull) ? 0.0f : 1.0f;
}

extern "C" void kernel_launch(void* const* d_in, const int* in_sizes, int n_in,
                              void* d_out, int out_size, void* d_ws, size_t ws_size,
                              hipStream_t stream) {
    (void)in_sizes; (void)n_in; (void)out_size;
    const float* s_f = (const float*)d_in[0];
    const float* t_f = (const float*)d_in[1];
    const float* gal = (const float*)d_in[2];
    float* out = (float*)d_out;

    char* ws = (char*)d_ws;
    const size_t off_tbf     = 0;                       // 131072
    const size_t off_partial = 131072;                  // 2621440
    const size_t off_topidx  = off_partial + 2621440;   // 2560
    const size_t off_bkmask  = off_topidx + 2560;       // 40960
    const size_t off_invn    = off_bkmask + 40960;      // 262144
    const size_t off_galbf   = off_invn + 262144;       // 67108864
    const size_t NEED        = off_galbf + 67108864;

    unsigned int* t_bf = (unsigned int*)(ws + off_tbf);
    float2* partial = (float2*)(ws + off_partial);
    int* top_idx = (int*)(ws + off_topidx);
    unsigned long long* bkmask = (unsigned long long*)(ws + off_bkmask);
    float* invnorm = (float*)(ws + off_invn);
    unsigned short* gal_bf = (unsigned short*)(ws + off_galbf);

    hipLaunchKernelGGL(k0_cvt_t, dim3(B * D / 4 / 256), dim3(256), 0, stream, t_f, t_bf);
    if (ws_size >= NEED) {
        hipLaunchKernelGGL(k0_cvt_g, dim3(N / 4), dim3(256), 0, stream,
                           gal, (uint4*)gal_bf, invnorm);
        hipLaunchKernelGGL(k1_dma, dim3(NBLK1), dim3(512), 0, stream,
                           (const unsigned short*)t_bf, gal_bf, invnorm, partial);
    } else {
        hipLaunchKernelGGL(k1_fb, dim3(NBLK1), dim3(512), 0, stream,
                           (const unsigned short*)t_bf, gal, partial);
    }
    hipLaunchKernelGGL(k2_merge, dim3(B), dim3(512), 0, stream, partial, top_idx);
    hipLaunchKernelGGL(k3_member, dim3(B * K), dim3(512), 0, stream,
                       s_f, gal, top_idx, bkmask);
    hipLaunchKernelGGL(k4_final, dim3(1), dim3(512), 0, stream, bkmask, out);
}

// Round 10
// 129.101 us; speedup vs baseline: 1.4192x; 1.3190x over previous
//
#include <hip/hip_runtime.h>

#define B 128
#define N 65536
#define D 512
#define K 5
#define M 256              // D * RATIO
#define GPB 256            // gallery rows per block (kernel1)
#define NBLK1 (N / GPB)    // 256 blocks
#define NW 16              // waves per k1 block

typedef __attribute__((ext_vector_type(8))) short short8;
typedef __attribute__((ext_vector_type(4))) float f32x4;
typedef __attribute__((address_space(1))) const unsigned char as1cu8;
typedef __attribute__((address_space(3))) unsigned char as3u8;

// pack two fp32 -> one u32 of 2 bf16 (truncation) via v_perm_b32.
__device__ __forceinline__ unsigned int pack_bf2(float lo, float hi) {
    return __builtin_amdgcn_perm(__float_as_uint(hi), __float_as_uint(lo), 0x07060302u);
}

__device__ __forceinline__ void top5_insert(float v, int gi, float tv[K], int ti[K]) {
    // descending by value, ties broken by lower index (matches lax.top_k)
    if (v > tv[K - 1] || (v == tv[K - 1] && gi < ti[K - 1])) {
        tv[K - 1] = v; ti[K - 1] = gi;
        #pragma unroll
        for (int k = K - 1; k > 0; --k) {
            bool sw = (tv[k] > tv[k - 1]) || (tv[k] == tv[k - 1] && ti[k] < ti[k - 1]);
            if (sw) {
                float fv = tv[k]; tv[k] = tv[k - 1]; tv[k - 1] = fv;
                int fi = ti[k]; ti[k] = ti[k - 1]; ti[k - 1] = fi;
            }
        }
    }
}

// packed-score insert (meta lives in low 8 mantissa bits; candidates distinct)
__device__ __forceinline__ void pk_insert(float sp, float lst[K]) {
    if (sp > lst[K - 1]) {
        lst[K - 1] = sp;
        #pragma unroll
        for (int k = K - 1; k > 0; --k)
            if (lst[k] > lst[k - 1]) {
                float t2 = lst[k]; lst[k] = lst[k - 1]; lst[k - 1] = t2;
            }
    }
}

// k0t: build t's MFMA B-fragments, bf16, LDS-ready linear layout:
// frag[(bt*16+ks)*64 + lane] = 8 bf16 of t[bt*16 + (lane&15)][ks*32 + (lane>>4)*8 ..+8]
__global__ __launch_bounds__(512) void k0_tfrag(const float* __restrict__ t_f,
                                                uint4* __restrict__ frag) {
    const int q = blockIdx.x * 512 + threadIdx.x;   // 0..8191
    const int bt = q >> 10;
    const int ks = (q >> 6) & 15;
    const int l = q & 63;
    const float* src = t_f + (size_t)(bt * 16 + (l & 15)) * D + ks * 32 + (l >> 4) * 8;
    float4 a = *reinterpret_cast<const float4*>(src);
    float4 b = *reinterpret_cast<const float4*>(src + 4);
    uint4 o;
    o.x = pack_bf2(a.x, a.y); o.y = pack_bf2(a.z, a.w);
    o.z = pack_bf2(b.x, b.y); o.w = pack_bf2(b.z, b.w);
    frag[q] = o;
}

// k1: A = gallery (streamed fp32 -> bf16 in-register), B = t (LDS fragments).
// 1024 threads = 16 waves (4/SIMD resident -> TLP hides HBM latency), wave w
// owns g-rows [blk*256 + 16w, +16) entirely; NO barriers in the main loop.
// D tile: row = l4*4+r = g-row, col = l15 = b-col -> 8 per-b top-5 lists/lane.
__global__ __launch_bounds__(1024) void k1_sims(const uint4* __restrict__ frag_t,
                                                const float* __restrict__ gal,
                                                float2* __restrict__ partial) {
    __shared__ __align__(16) char smem[NW * 8 * 1024];   // 131072 B: t-frags, then merge buf

    const int tid = threadIdx.x;
    const int blk = blockIdx.x;
    const int lane = tid & 63;
    const int w = tid >> 6;
    const int l15 = lane & 15;
    const int l4 = lane >> 4;

    // ---- stage t-frags: 128KB linear global_load_lds ----
    {
        const char* src = reinterpret_cast<const char*>(frag_t);
        #pragma unroll
        for (int i = 0; i < 8; ++i) {
            const char* s = src + i * 16384 + w * 1024 + lane * 16;
            char* d = smem + i * 16384 + w * 1024;      // wave-uniform; HW adds lane*16
            __builtin_amdgcn_global_load_lds((as1cu8*)s, (as3u8*)d, 16, 0, 0);
        }
    }

    // lane's gallery row + k-quarter
    const int grow = blk * GPB + w * 16 + l15;
    const float* gp = gal + (size_t)grow * D + l4 * 8;

    // issue first k-slice loads before the barrier (overlap DMA drain)
    float4 c0 = *reinterpret_cast<const float4*>(gp);
    float4 c1 = *reinterpret_cast<const float4*>(gp + 4);

    f32x4 acc[8];
    #pragma unroll
    for (int bt = 0; bt < 8; ++bt) acc[bt] = (f32x4)0.0f;
    float lst[8][K];
    #pragma unroll
    for (int bt = 0; bt < 8; ++bt)
        #pragma unroll
        for (int k = 0; k < K; ++k) lst[bt][k] = -1e30f;
    float nrm = 0.0f;

    __syncthreads();   // t-frags ready (single block-wide barrier)

    #pragma unroll
    for (int ks = 0; ks < 16; ++ks) {
        float4 n0 = c0, n1 = c1;
        if (ks < 15) {
            n0 = *reinterpret_cast<const float4*>(gp + (ks + 1) * 32);
            n1 = *reinterpret_cast<const float4*>(gp + (ks + 1) * 32 + 4);
        }
        nrm = fmaf(c0.x, c0.x, nrm); nrm = fmaf(c0.y, c0.y, nrm);
        nrm = fmaf(c0.z, c0.z, nrm); nrm = fmaf(c0.w, c0.w, nrm);
        nrm = fmaf(c1.x, c1.x, nrm); nrm = fmaf(c1.y, c1.y, nrm);
        nrm = fmaf(c1.z, c1.z, nrm); nrm = fmaf(c1.w, c1.w, nrm);
        uint4 qq;
        qq.x = pack_bf2(c0.x, c0.y); qq.y = pack_bf2(c0.z, c0.w);
        qq.z = pack_bf2(c1.x, c1.y); qq.w = pack_bf2(c1.z, c1.w);
        short8 afrag = *reinterpret_cast<short8*>(&qq);
        #pragma unroll
        for (int bt = 0; bt < 8; ++bt) {
            short8 tf = *reinterpret_cast<const short8*>(smem + (bt * 16 + ks) * 1024 + lane * 16);
            acc[bt] = __builtin_amdgcn_mfma_f32_16x16x32_bf16(afrag, tf, acc[bt], 0, 0, 0);
        }
        c0 = n0; c1 = n1;
    }

    // full row norm: sum the 4 k-quarters (lanes sharing l15)
    nrm += __shfl_xor(nrm, 16);
    nrm += __shfl_xor(nrm, 32);
    float invn = rsqrtf(fmaxf(nrm, 1e-24f));

    // scale for acc row r (g-row l4*4+r): norm lives on lane (l4*4+r)
    float sc[4];
    #pragma unroll
    for (int r = 0; r < 4; ++r) sc[r] = __shfl(invn, l4 * 4 + r);

    // insert: candidate g = w*16 + l4*4 + r (8-bit meta within block), per b-list bt
    #pragma unroll
    for (int bt = 0; bt < 8; ++bt)
        #pragma unroll
        for (int r = 0; r < 4; ++r) {
            float s = acc[bt][r] * sc[r];
            unsigned meta = (unsigned)(w * 16 + l4 * 4 + r);
            float sp = __uint_as_float((__float_as_uint(s) & 0xFFFFFF00u) | meta);
            pk_insert(sp, lst[bt]);
        }

    // merge across the 4 lanes sharing l15 (masks 16, 32)
    #pragma unroll
    for (int mk = 16; mk <= 32; mk <<= 1)
        #pragma unroll
        for (int bt = 0; bt < 8; ++bt) {
            float inc[K];
            #pragma unroll
            for (int k = 0; k < K; ++k) inc[k] = __shfl_xor(lst[bt][k], mk);
            #pragma unroll
            for (int k = 0; k < K; ++k) pk_insert(inc[k], lst[bt]);
        }

    // ---- in-block cross-wave merge (smem reused; all t-frag reads done) ----
    __syncthreads();
    float* mbuf = reinterpret_cast<float*>(smem);   // [16 waves][128 b][5]
    if (l4 == 0) {
        #pragma unroll
        for (int bt = 0; bt < 8; ++bt)
            #pragma unroll
            for (int k = 0; k < K; ++k)
                mbuf[((size_t)w * B + bt * 16 + l15) * K + k] = lst[bt][k];
    }
    __syncthreads();
    {
        const int b = tid >> 3, sub = tid & 7;
        float mv[K];
        #pragma unroll
        for (int k = 0; k < K; ++k) mv[k] = -1e30f;
        #pragma unroll
        for (int u = 0; u < 2; ++u) {
            const int wv = sub * 2 + u;
            #pragma unroll
            for (int k = 0; k < K; ++k) pk_insert(mbuf[((size_t)wv * B + b) * K + k], mv);
        }
        #pragma unroll
        for (int mk = 1; mk <= 4; mk <<= 1) {
            float inc[K];
            #pragma unroll
            for (int k = 0; k < K; ++k) inc[k] = __shfl_xor(mv[k], mk);
            #pragma unroll
            for (int k = 0; k < K; ++k) pk_insert(inc[k], mv);
        }
        if (sub == 0) {
            #pragma unroll
            for (int k = 0; k < K; ++k) {
                unsigned sp = __float_as_uint(mv[k]);
                int g = blk * GPB + (int)(sp & 0xFFu);
                partial[((size_t)b * NBLK1 + blk) * K + k] = make_float2(mv[k], __int_as_float(g));
            }
        }
    }
}

// k2: merge 256 partial top-5 lists per batch row -> top_idx. Shuffle-first.
__global__ __launch_bounds__(512) void k2_merge(const float2* __restrict__ partial,
                                                int* __restrict__ top_idx) {
    __shared__ float2 wlist[8][K];
    const int b = blockIdx.x;
    const int p = threadIdx.x;
    const int lane = p & 63;
    const int w = p >> 6;

    float mv[K]; int mi[K];
    #pragma unroll
    for (int k = 0; k < K; ++k) { mv[k] = -1e30f; mi[k] = 0x7fffffff; }
    if (p < NBLK1) {
        #pragma unroll
        for (int k = 0; k < K; ++k) {
            float2 c = partial[((size_t)b * NBLK1 + p) * K + k];
            mv[k] = c.x; mi[k] = __float_as_int(c.y);
        }
    }
    #pragma unroll
    for (int mk = 1; mk <= 32; mk <<= 1) {
        float ov[K]; int oi[K];
        #pragma unroll
        for (int k = 0; k < K; ++k) { ov[k] = __shfl_xor(mv[k], mk); oi[k] = __shfl_xor(mi[k], mk); }
        #pragma unroll
        for (int k = 0; k < K; ++k) top5_insert(ov[k], oi[k], mv, mi);
    }
    if (lane == 0) {
        #pragma unroll
        for (int k = 0; k < K; ++k) wlist[w][k] = make_float2(mv[k], __int_as_float(mi[k]));
    }
    __syncthreads();
    if (w == 0) {
        #pragma unroll
        for (int k = 0; k < K; ++k) { mv[k] = -1e30f; mi[k] = 0x7fffffff; }
        if (lane < 8) {
            #pragma unroll
            for (int k = 0; k < K; ++k) {
                float2 c = wlist[lane][k];
                mv[k] = c.x; mi[k] = __float_as_int(c.y);
            }
        }
        #pragma unroll
        for (int mk = 1; mk <= 4; mk <<= 1) {
            float ov[K]; int oi[K];
            #pragma unroll
            for (int k = 0; k < K; ++k) { ov[k] = __shfl_xor(mv[k], mk); oi[k] = __shfl_xor(mi[k], mk); }
            #pragma unroll
            for (int k = 0; k < K; ++k) top5_insert(ov[k], oi[k], mv, mi);
        }
        if (lane == 0) {
            #pragma unroll
            for (int k = 0; k < K; ++k) top_idx[b * K + k] = mi[k];
        }
    }
}

// k3: one block per (b,k) row: bottom-m membership of |gal[row,c]*s_f[b,c]|
// (per-row norms are positive constants -> ordering matches the reference's
// normalized products). Plain stores; kernel-boundary coherence (R8 lesson).
__global__ __launch_bounds__(512) void k3_member(const float* __restrict__ s_f,
                                                 const float* __restrict__ gal,
                                                 const int* __restrict__ top_idx,
                                                 unsigned long long* __restrict__ bkmask) {
    __shared__ __align__(16) float pS[D];
    const int p = threadIdx.x;
    const int bk = blockIdx.x;
    const int b = bk / K;
    const int row = top_idx[bk];
    float pv = fabsf(gal[(size_t)row * D + p] * s_f[(size_t)b * D + p]);
    pS[p] = pv;
    __syncthreads();
    int cnt = 0;
    const float4* p4 = reinterpret_cast<const float4*>(pS);
    #pragma unroll 4
    for (int j = 0; j < D / 4; ++j) {
        float4 o = p4[j];
        cnt += (o.x < pv || (o.x == pv && (4 * j + 0) < p)) ? 1 : 0;
        cnt += (o.y < pv || (o.y == pv && (4 * j + 1) < p)) ? 1 : 0;
        cnt += (o.z < pv || (o.z == pv && (4 * j + 2) < p)) ? 1 : 0;
        cnt += (o.w < pv || (o.w == pv && (4 * j + 3) < p)) ? 1 : 0;
    }
    unsigned long long bm = __ballot(cnt < M);
    if ((p & 63) == 0) bkmask[(size_t)bk * 8 + (p >> 6)] = bm;
}

// k4: AND-reduce the 640 per-(b,k) masks, emit the output mask. 40 KB, L2-hot.
__global__ __launch_bounds__(512) void k4_final(const unsigned long long* __restrict__ bkmask,
                                                float* __restrict__ out) {
    const int c = threadIdx.x;
    const int word = c >> 6, bit = c & 63;
    unsigned long long acc = ~0ull;
    for (int bk = 0; bk < B * K; bk += 4) {
        acc &= bkmask[(size_t)bk * 8 + word];
        acc &= bkmask[(size_t)(bk + 1) * 8 + word];
        acc &= bkmask[(size_t)(bk + 2) * 8 + word];
        acc &= bkmask[(size_t)(bk + 3) * 8 + word];
    }
    out[c] = ((acc >> bit) & 1ull) ? 0.0f : 1.0f;
}

extern "C" void kernel_launch(void* const* d_in, const int* in_sizes, int n_in,
                              void* d_out, int out_size, void* d_ws, size_t ws_size,
                              hipStream_t stream) {
    (void)in_sizes; (void)n_in; (void)out_size; (void)ws_size;
    const float* s_f = (const float*)d_in[0];
    const float* t_f = (const float*)d_in[1];
    const float* gal = (const float*)d_in[2];
    float* out = (float*)d_out;

    char* ws = (char*)d_ws;
    const size_t off_frag    = 0;                        // 131072
    const size_t off_partial = 131072;                   // 128*256*5*8 = 1310720
    const size_t off_topidx  = off_partial + 1310720;    // 2560
    const size_t off_bkmask  = off_topidx + 2560;        // 40960

    uint4* frag_t = (uint4*)(ws + off_frag);
    float2* partial = (float2*)(ws + off_partial);
    int* top_idx = (int*)(ws + off_topidx);
    unsigned long long* bkmask = (unsigned long long*)(ws + off_bkmask);

    hipLaunchKernelGGL(k0_tfrag, dim3(16), dim3(512), 0, stream, t_f, frag_t);
    hipLaunchKernelGGL(k1_sims, dim3(NBLK1), dim3(1024), 0, stream, frag_t, gal, partial);
    hipLaunchKernelGGL(k2_merge, dim3(B), dim3(512), 0, stream, partial, top_idx);
    hipLaunchKernelGGL(k3_member, dim3(B * K), dim3(512), 0, stream, s_f, gal, top_idx, bkmask);
    hipLaunchKernelGGL(k4_final, dim3(1), dim3(512), 0, stream, bkmask, out);
}